// Round 7
// baseline (3408.003 us; speedup 1.0000x reference)
//
#include <hip/hip_runtime.h>

typedef _Float16 f16x8 __attribute__((ext_vector_type(8)));
typedef float    f32x4 __attribute__((ext_vector_type(4)));

namespace {
constexpr int Bb = 8, Cc = 256, Oo = 256;
constexpr int HW = 4096;                 // 64x64
constexpr int NCHUNK = 72;               // 2304 / 32
constexpr int SROW = 40;                 // Sl row stride (f16), pad 32->40
}

__device__ inline f16x8 sp8(_Float16 x) { f16x8 r = {x,x,x,x,x,x,x,x}; return r; }

// ---------- pre-kernel 1: NCHW fp32 -> NHWC fp16 ----------
__global__ __launch_bounds__(256)
void nchw_to_nhwc_f16(const float* __restrict__ in, _Float16* __restrict__ outh) {
  const int tid = threadIdx.x;
  const int b   = blockIdx.y;
  const int px  = blockIdx.x * 32 + (tid >> 3);
  const int c8s = tid & 7;
  const float* src = in + (size_t)b * Cc * HW + px;
  _Float16*    dst = outh + ((size_t)b * HW + px) * Cc;
#pragma unroll
  for (int q = 0; q < 4; ++q) {
    int c8 = q * 8 + c8s;
    f16x8 v;
#pragma unroll
    for (int j = 0; j < 8; ++j)
      v[j] = (_Float16)src[(size_t)(c8 * 8 + j) * HW];
    *(f16x8*)(dst + c8 * 8) = v;
  }
}

// ---------- pre-kernel 2: weight fp32 [O][C][9] -> fp16 [chunk][kq][o][k8] ----------
__global__ __launch_bounds__(256)
void wcvt(const float* __restrict__ w, _Float16* __restrict__ wh) {
  int t   = blockIdx.x * 256 + threadIdx.x;   // 0..73727
  int o   = t & 255;
  int Kb  = (t >> 8) * 8;
  const float* s = w + (size_t)o * 2304;
  f16x8 v;
#pragma unroll
  for (int k8 = 0; k8 < 8; ++k8) {
    int K = Kb + k8;
    int tap = K >> 8, c = K & 255;
    v[k8] = (_Float16)s[c * 9 + tap];
  }
  *(f16x8*)(wh + (size_t)t * 8) = v;
}

// ---------- main kernel: 256(o) x 64(p), 256 thr, 2 blocks/CU, depth-2 gather pipe ----------
// grid (x=b, y=row): linear%8 = b -> XCD-affine. Weights global->register (no W LDS).
__global__ __launch_bounds__(256, 2)
void dcn_mfma(const _Float16* __restrict__ inh,   // [B][4096][256] fp16 NHWC
              const _Float16* __restrict__ wgh,   // [72][4][256][8] fp16 (A-frag order)
              const float* __restrict__ offset,
              const float* __restrict__ mask,
              const float* __restrict__ bias,
              float* __restrict__ out) {
  __shared__ __align__(16) _Float16 Sl[2][64 * SROW];  // 10.25 KB total

  const int tid = threadIdx.x;
  const int b   = blockIdx.x;   // 0..7  -> XCD
  const int rp  = blockIdx.y;   // 0..63 -> one output row

  // sampling role: 64 pos x 4 channel-octets (4 lanes = 64 B contiguous per pixel)
  const int pos = tid >> 2, cg = tid & 3;
  const int ho  = rp, wo = pos;
  // MFMA role: 4 waves, each 64(o) x 64(p)
  const int lane = tid & 63, wm = tid >> 6;
  const int lq = lane >> 4, lr = lane & 15;

  const f16x8* gin = (const f16x8*)(inh + (size_t)b * HW * Cc);
  const uint4* wg4 = (const uint4*)wgh;
  const int    wbase = lq * 256 + wm * 64 + lr;   // uint4 index within chunk

  // double-buffered sampling metadata (slot = tap & 1)
  int4   mi[2];  float4 mwt[2];
  float  ofy, ofx, msk;          // md inputs, loaded 2 chunks ahead of build
  f16x8  vc[2][4];               // depth-2 corner register sets (set = chunk & 1)
  uint4  awv[4];                 // A-fragments in flight (depth 1)

  auto load_md_inputs = [&](int tap) {
    ofy = offset[(((size_t)b * 18 + 2 * tap)     * 64 + ho) * 64 + wo];
    ofx = offset[(((size_t)b * 18 + 2 * tap + 1) * 64 + ho) * 64 + wo];
    msk = mask  [(((size_t)b * 9  + tap)         * 64 + ho) * 64 + wo];
  };
  auto build_md = [&](int tap) {
    int sl = tap & 1;
    int ki = tap / 3, kj = tap % 3;
    float y = ofy + (float)(ho - 1 + ki);
    float x = ofx + (float)(wo - 1 + kj);
    float y0f = floorf(y), x0f = floorf(x);
    float ly = y - y0f, lx = x - x0f;
    float hy = 1.f - ly, hx = 1.f - lx;
    int y0 = (int)y0f, x0 = (int)x0f;
    int y1 = y0 + 1, x1 = x0 + 1;
    bool vy0 = (unsigned)y0 < 64u, vy1 = (unsigned)y1 < 64u;
    bool vx0 = (unsigned)x0 < 64u, vx1 = (unsigned)x1 < 64u;
    int cy0 = min(max(y0, 0), 63), cy1 = min(max(y1, 0), 63);
    int cx0 = min(max(x0, 0), 63), cx1 = min(max(x1, 0), 63);
    mwt[sl].x = (vy0 && vx0) ? hy * hx * msk : 0.f;
    mwt[sl].y = (vy0 && vx1) ? hy * lx * msk : 0.f;
    mwt[sl].z = (vy1 && vx0) ? ly * hx * msk : 0.f;
    mwt[sl].w = (vy1 && vx1) ? ly * lx * msk : 0.f;
    mi[sl] = make_int4(cy0 * 64 + cx0, cy0 * 64 + cx1, cy1 * 64 + cx0, cy1 * 64 + cx1);
  };
  auto gather = [&](int g) {               // into set g&1, md slot (g>>3)&1
    const int4 m = mi[(g >> 3) & 1];
    const int  set = g & 1;
    int cb = (g & 7) * 4 + cg;
    vc[set][0] = gin[m.x * 32 + cb];
    vc[set][1] = gin[m.y * 32 + cb];
    vc[set][2] = gin[m.z * 32 + cb];
    vc[set][3] = gin[m.w * 32 + cb];
  };
  auto stage = [&](int s) {                // consume set s&1, weights slot (s>>3)&1
    const float4 w = mwt[(s >> 3) & 1];
    const int set = s & 1;
    f16x8 sv = vc[set][0] * sp8((_Float16)w.x) + vc[set][1] * sp8((_Float16)w.y)
             + vc[set][2] * sp8((_Float16)w.z) + vc[set][3] * sp8((_Float16)w.w);
    *(f16x8*)(&Sl[s & 1][pos * SROW + cg * 8]) = sv;
  };
  auto wload = [&](int c) {
    const uint4* base = wg4 + (size_t)c * 1024 + wbase;
#pragma unroll
    for (int mt = 0; mt < 4; ++mt) awv[mt] = base[mt * 16];
  };

  f32x4 acc[4][4];
#pragma unroll
  for (int mt = 0; mt < 4; ++mt)
#pragma unroll
    for (int nt = 0; nt < 4; ++nt) {
      acc[mt][nt][0] = 0.f; acc[mt][nt][1] = 0.f;
      acc[mt][nt][2] = 0.f; acc[mt][nt][3] = 0.f;
    }

  // ---- prologue: md(tap0), gather chunks 0 & 1, weights 0, stage 0 ----
  load_md_inputs(0);
  build_md(0);
  gather(0);
  wload(0);
  gather(1);
  stage(0);                      // waits on set 0; set-1/wload stay in flight
  __syncthreads();

  for (int c = 0; c < NCHUNK; ++c) {
    const int cur = c & 1;

    // issue gathers for chunk c+2 (earliest -> longest latency budget)
    if (c + 2 < NCHUNK) {
      if (((c + 2) & 7) == 0) build_md((c + 2) >> 3);
      gather(c + 2);             // into set c&1 (freed by stage(c) last iter)
    }
    // md inputs for the NEXT tap, 2 chunks before its build
    if ((c & 7) == 4) {
      int t = (c >> 3) + 1;
      if (t < 9) load_md_inputs(t);
    }

    // A-fragments for this chunk (loaded last iter), then prefetch next
    f16x8 afr[4];
#pragma unroll
    for (int mt = 0; mt < 4; ++mt) afr[mt] = __builtin_bit_cast(f16x8, awv[mt]);
    if (c + 1 < NCHUNK) wload(c + 1);

    const _Float16* SlB = &Sl[cur][lr * SROW + lq * 8];
#pragma unroll
    for (int nt = 0; nt < 4; ++nt) {
      f16x8 bfr = *(const f16x8*)(SlB + nt * 16 * SROW);
#pragma unroll
      for (int mt = 0; mt < 4; ++mt)
        acc[mt][nt] = __builtin_amdgcn_mfma_f32_16x16x32_f16(afr[mt], bfr, acc[mt][nt], 0, 0, 0);
    }

    if (c + 1 < NCHUNK) stage(c + 1);   // consume set (c+1)&1 -> Sl[cur^1]
    __syncthreads();
  }

  // ---- epilogue: bias + store ----
#pragma unroll
  for (int mt = 0; mt < 4; ++mt) {
#pragma unroll
    for (int reg = 0; reg < 4; ++reg) {
      int o = wm * 64 + mt * 16 + lq * 4 + reg;
      float bv = bias[o];
      float* op = out + ((size_t)(b * 256 + o)) * 4096 + rp * 64 + lr;
#pragma unroll
      for (int nt = 0; nt < 4; ++nt)
        op[nt * 16] = acc[mt][nt][reg] + bv;
    }
  }
}

extern "C" void kernel_launch(void* const* d_in, const int* in_sizes, int n_in,
                              void* d_out, int out_size, void* d_ws, size_t ws_size,
                              hipStream_t stream) {
  const float* inp    = (const float*)d_in[0];
  const float* offset = (const float*)d_in[1];
  const float* mask   = (const float*)d_in[2];
  const float* weight = (const float*)d_in[3];
  const float* bias   = (const float*)d_in[4];
  float* out = (float*)d_out;

  _Float16* inh = (_Float16*)d_ws;                       // 16.78 MB
  _Float16* wgh = inh + (size_t)Bb * HW * Cc;            // +1.18 MB

  hipLaunchKernelGGL(nchw_to_nhwc_f16, dim3(128, Bb), dim3(256), 0, stream, inp, inh);
  hipLaunchKernelGGL(wcvt, dim3(288), dim3(256), 0, stream, weight, wgh);
  // grid: x=b -> linear%8 = batch -> XCD-affine; y = output row; 2 blocks/CU
  hipLaunchKernelGGL(dcn_mfma, dim3(Bb, 64), dim3(256), 0, stream,
                     inh, wgh, offset, mask, bias, out);
}

// Round 8
// 155.513 us; speedup vs baseline: 21.9145x; 21.9145x over previous
//
#include <hip/hip_runtime.h>

typedef _Float16 f16x8 __attribute__((ext_vector_type(8)));
typedef float    f32x4 __attribute__((ext_vector_type(4)));

namespace {
constexpr int Bb = 8, Cc = 256, Oo = 256;
constexpr int HW = 4096;                 // 64x64
constexpr int NCHUNK = 72;               // 2304 / 32
constexpr int SROW = 40;                 // Sl row stride (f16), pad 32->40
}

__device__ inline f16x8 sp8(_Float16 x) { f16x8 r = {x,x,x,x,x,x,x,x}; return r; }

// ---------- pre-kernel 1: NCHW fp32 -> NHWC fp16 ----------
__global__ __launch_bounds__(256)
void nchw_to_nhwc_f16(const float* __restrict__ in, _Float16* __restrict__ outh) {
  const int tid = threadIdx.x;
  const int b   = blockIdx.y;
  const int px  = blockIdx.x * 32 + (tid >> 3);
  const int c8s = tid & 7;
  const float* src = in + (size_t)b * Cc * HW + px;
  _Float16*    dst = outh + ((size_t)b * HW + px) * Cc;
#pragma unroll
  for (int q = 0; q < 4; ++q) {
    int c8 = q * 8 + c8s;
    f16x8 v;
#pragma unroll
    for (int j = 0; j < 8; ++j)
      v[j] = (_Float16)src[(size_t)(c8 * 8 + j) * HW];
    *(f16x8*)(dst + c8 * 8) = v;
  }
}

// ---------- pre-kernel 2: weight fp32 [O][C][9] -> fp16 [chunk][kq][o][k8] ----------
__global__ __launch_bounds__(256)
void wcvt(const float* __restrict__ w, _Float16* __restrict__ wh) {
  int t   = blockIdx.x * 256 + threadIdx.x;   // 0..73727
  int o   = t & 255;
  int Kb  = (t >> 8) * 8;
  const float* s = w + (size_t)o * 2304;
  f16x8 v;
#pragma unroll
  for (int k8 = 0; k8 < 8; ++k8) {
    int K = Kb + k8;
    int tap = K >> 8, c = K & 255;
    v[k8] = (_Float16)s[c * 9 + tap];
  }
  *(f16x8*)(wh + (size_t)t * 8) = v;
}

// ---------- main kernel: 256(o) x 64(p), 256 thr, 2 blocks/CU, depth-2 pipe ----------
// tap-loop x fully-unrolled 8-chunk inner loop: ALL register-array indices static.
__global__ __launch_bounds__(256, 2)
void dcn_mfma(const _Float16* __restrict__ inh,   // [B][4096][256] fp16 NHWC
              const _Float16* __restrict__ wgh,   // [72][4][256][8] fp16 (A-frag order)
              const float* __restrict__ offset,
              const float* __restrict__ mask,
              const float* __restrict__ bias,
              float* __restrict__ out) {
  __shared__ __align__(16) _Float16 Sl[2][64 * SROW];  // 10.25 KB

  const int tid = threadIdx.x;
  const int b   = blockIdx.x;   // 0..7  -> linear%8 -> XCD-affine batch
  const int rp  = blockIdx.y;   // 0..63 -> one output row

  // sampling role: 64 pos x 4 channel-octets (4 lanes = 64 B contiguous per pixel)
  const int pos = tid >> 2, cg = tid & 3;
  const int ho  = rp, wo = pos;
  // MFMA role: 4 waves, each 64(o) x 64(p)
  const int lane = tid & 63, wm = tid >> 6;
  const int lq = lane >> 4, lr = lane & 15;

  const f16x8* gin = (const f16x8*)(inh + (size_t)b * HW * Cc);
  const uint4* wg4 = (const uint4*)wgh;
  const int    wbase = lq * 256 + wm * 64 + lr;   // uint4 index within chunk

  int4   mi_c, mi_n = {0,0,0,0};
  float4 mwt_c, mwt_n = {0,0,0,0};
  float  ofy, ofx, msk;
  f16x8  vc[2][4];               // depth-2 corner sets — static indices only
  uint4  awv[4];

  auto load_md_inputs = [&](int tap) {
    ofy = offset[(((size_t)b * 18 + 2 * tap)     * 64 + ho) * 64 + wo];
    ofx = offset[(((size_t)b * 18 + 2 * tap + 1) * 64 + ho) * 64 + wo];
    msk = mask  [(((size_t)b * 9  + tap)         * 64 + ho) * 64 + wo];
  };
  auto build_md = [&](int tap, int4& mio, float4& mwo) {
    int ki = tap / 3, kj = tap % 3;
    float y = ofy + (float)(ho - 1 + ki);
    float x = ofx + (float)(wo - 1 + kj);
    float y0f = floorf(y), x0f = floorf(x);
    float ly = y - y0f, lx = x - x0f;
    float hy = 1.f - ly, hx = 1.f - lx;
    int y0 = (int)y0f, x0 = (int)x0f;
    int y1 = y0 + 1, x1 = x0 + 1;
    bool vy0 = (unsigned)y0 < 64u, vy1 = (unsigned)y1 < 64u;
    bool vx0 = (unsigned)x0 < 64u, vx1 = (unsigned)x1 < 64u;
    int cy0 = min(max(y0, 0), 63), cy1 = min(max(y1, 0), 63);
    int cx0 = min(max(x0, 0), 63), cx1 = min(max(x1, 0), 63);
    mwo.x = (vy0 && vx0) ? hy * hx * msk : 0.f;
    mwo.y = (vy0 && vx1) ? hy * lx * msk : 0.f;
    mwo.z = (vy1 && vx0) ? ly * hx * msk : 0.f;
    mwo.w = (vy1 && vx1) ? ly * lx * msk : 0.f;
    mio = make_int4(cy0 * 64 + cx0, cy0 * 64 + cx1, cy1 * 64 + cx0, cy1 * 64 + cx1);
  };
  auto gather = [&](const int4& m, int cb8, f16x8* dst) {
    int cb = cb8 + cg;
    dst[0] = gin[m.x * 32 + cb];
    dst[1] = gin[m.y * 32 + cb];
    dst[2] = gin[m.z * 32 + cb];
    dst[3] = gin[m.w * 32 + cb];
  };
  auto stage = [&](const f16x8* v, const float4& w, int buf) {
    f16x8 sv = v[0] * sp8((_Float16)w.x) + v[1] * sp8((_Float16)w.y)
             + v[2] * sp8((_Float16)w.z) + v[3] * sp8((_Float16)w.w);
    *(f16x8*)(&Sl[buf][pos * SROW + cg * 8]) = sv;
  };
  auto wload = [&](int c) {
    const uint4* base = wg4 + (size_t)c * 1024 + wbase;
#pragma unroll
    for (int mt = 0; mt < 4; ++mt) awv[mt] = base[mt * 16];
  };

  f32x4 acc[4][4];
#pragma unroll
  for (int mt = 0; mt < 4; ++mt)
#pragma unroll
    for (int nt = 0; nt < 4; ++nt) {
      acc[mt][nt][0] = 0.f; acc[mt][nt][1] = 0.f;
      acc[mt][nt][2] = 0.f; acc[mt][nt][3] = 0.f;
    }

  // ---- prologue: md(tap0), gather chunks 0,1, weights 0, stage chunk 0 ----
  load_md_inputs(0);
  build_md(0, mi_c, mwt_c);
  gather(mi_c, 0, vc[0]);          // chunk 0 -> set 0
  wload(0);
  gather(mi_c, 4, vc[1]);          // chunk 1 -> set 1
  stage(vc[0], mwt_c, 0);          // Sl[0]
  __syncthreads();

  for (int t = 0; t < 9; ++t) {
#pragma unroll
    for (int j = 0; j < 8; ++j) {          // c = t*8 + j ; all j-indices fold
      const int c   = t * 8 + j;
      const int cur = j & 1;               // == c & 1

      // gathers for chunk c+2 -> set cur (freed by stage(c) last iteration)
      if (j < 6) {
        gather(mi_c, ((j + 2) & 7) * 4, vc[cur]);
      } else if (t < 8) {
        if (j == 6) build_md(t + 1, mi_n, mwt_n);   // inputs loaded at j==4
        gather(mi_n, ((j + 2) & 7) * 4, vc[cur]);
      }
      if (j == 4 && t < 8) load_md_inputs(t + 1);   // 2 chunks ahead of build

      // A-fragments for this chunk (loaded last iteration), then prefetch next
      f16x8 afr[4];
#pragma unroll
      for (int mt = 0; mt < 4; ++mt) afr[mt] = __builtin_bit_cast(f16x8, awv[mt]);
      if (j < 7 || t < 8) wload(c + 1);

      const _Float16* SlB = &Sl[cur][lr * SROW + lq * 8];
#pragma unroll
      for (int nt = 0; nt < 4; ++nt) {
        f16x8 bfr = *(const f16x8*)(SlB + nt * 16 * SROW);
#pragma unroll
        for (int mt = 0; mt < 4; ++mt)
          acc[mt][nt] = __builtin_amdgcn_mfma_f32_16x16x32_f16(afr[mt], bfr, acc[mt][nt], 0, 0, 0);
      }

      // stage chunk c+1 (consume set cur^1) into Sl[cur^1]
      if (j < 7) {
        stage(vc[cur ^ 1], mwt_c, cur ^ 1);
      } else if (t < 8) {
        stage(vc[cur ^ 1], mwt_n, cur ^ 1);         // c+1 starts tap t+1
      }
      __syncthreads();
    }
    if (t < 8) { mi_c = mi_n; mwt_c = mwt_n; }      // rotate md registers
  }

  // ---- epilogue: bias + store ----
#pragma unroll
  for (int mt = 0; mt < 4; ++mt) {
#pragma unroll
    for (int reg = 0; reg < 4; ++reg) {
      int o = wm * 64 + mt * 16 + lq * 4 + reg;
      float bv = bias[o];
      float* op = out + ((size_t)(b * 256 + o)) * 4096 + rp * 64 + lr;
#pragma unroll
      for (int nt = 0; nt < 4; ++nt)
        op[nt * 16] = acc[mt][nt][reg] + bv;
    }
  }
}

extern "C" void kernel_launch(void* const* d_in, const int* in_sizes, int n_in,
                              void* d_out, int out_size, void* d_ws, size_t ws_size,
                              hipStream_t stream) {
  const float* inp    = (const float*)d_in[0];
  const float* offset = (const float*)d_in[1];
  const float* mask   = (const float*)d_in[2];
  const float* weight = (const float*)d_in[3];
  const float* bias   = (const float*)d_in[4];
  float* out = (float*)d_out;

  _Float16* inh = (_Float16*)d_ws;                       // 16.78 MB
  _Float16* wgh = inh + (size_t)Bb * HW * Cc;            // +1.18 MB

  hipLaunchKernelGGL(nchw_to_nhwc_f16, dim3(128, Bb), dim3(256), 0, stream, inp, inh);
  hipLaunchKernelGGL(wcvt, dim3(288), dim3(256), 0, stream, weight, wgh);
  // grid: x=b -> linear%8 = batch -> XCD-affine; y = output row; 2 blocks/CU
  hipLaunchKernelGGL(dcn_mfma, dim3(Bb, 64), dim3(256), 0, stream,
                     inh, wgh, offset, mask, bias, out);
}

// Round 9
// 153.469 us; speedup vs baseline: 22.2065x; 1.0133x over previous
//
#include <hip/hip_runtime.h>

typedef _Float16 f16x8 __attribute__((ext_vector_type(8)));
typedef float    f32x4 __attribute__((ext_vector_type(4)));

namespace {
constexpr int Bb = 8, Cc = 256, Oo = 256;
constexpr int HW = 4096;                 // 64x64
constexpr int NCHUNK = 72;               // 2304 / 32
constexpr int SROW = 40;                 // Sl row stride (f16), pad 32->40
}

__device__ inline f16x8 sp8(_Float16 x) { f16x8 r = {x,x,x,x,x,x,x,x}; return r; }

// Workgroup barrier WITHOUT the vmcnt(0) drain __syncthreads() emits.
// LDS ops are drained (lgkmcnt(0)) so Sl handoff is safe; global loads
// issued before the barrier stay in flight (consumers carry their own waits).
__device__ inline void barrier_no_vm_drain() {
  asm volatile("s_waitcnt lgkmcnt(0)\n\ts_barrier" ::: "memory");
}

// ---------- pre-kernel 1: NCHW fp32 -> NHWC fp16 ----------
__global__ __launch_bounds__(256)
void nchw_to_nhwc_f16(const float* __restrict__ in, _Float16* __restrict__ outh) {
  const int tid = threadIdx.x;
  const int b   = blockIdx.y;
  const int px  = blockIdx.x * 32 + (tid >> 3);
  const int c8s = tid & 7;
  const float* src = in + (size_t)b * Cc * HW + px;
  _Float16*    dst = outh + ((size_t)b * HW + px) * Cc;
#pragma unroll
  for (int q = 0; q < 4; ++q) {
    int c8 = q * 8 + c8s;
    f16x8 v;
#pragma unroll
    for (int j = 0; j < 8; ++j)
      v[j] = (_Float16)src[(size_t)(c8 * 8 + j) * HW];
    *(f16x8*)(dst + c8 * 8) = v;
  }
}

// ---------- pre-kernel 2: weight fp32 [O][C][9] -> fp16 [chunk][kq][o][k8] ----------
__global__ __launch_bounds__(256)
void wcvt(const float* __restrict__ w, _Float16* __restrict__ wh) {
  int t   = blockIdx.x * 256 + threadIdx.x;   // 0..73727
  int o   = t & 255;
  int Kb  = (t >> 8) * 8;
  const float* s = w + (size_t)o * 2304;
  f16x8 v;
#pragma unroll
  for (int k8 = 0; k8 < 8; ++k8) {
    int K = Kb + k8;
    int tap = K >> 8, c = K & 255;
    v[k8] = (_Float16)s[c * 9 + tap];
  }
  *(f16x8*)(wh + (size_t)t * 8) = v;
}

// ---------- main kernel: 256(o) x 64(p), 256 thr, 2 blocks/CU, depth-2 pipe ----------
// R8 + raw barrier (no vmcnt drain): gathers genuinely live across the barrier.
__global__ __launch_bounds__(256, 2)
void dcn_mfma(const _Float16* __restrict__ inh,   // [B][4096][256] fp16 NHWC
              const _Float16* __restrict__ wgh,   // [72][4][256][8] fp16 (A-frag order)
              const float* __restrict__ offset,
              const float* __restrict__ mask,
              const float* __restrict__ bias,
              float* __restrict__ out) {
  __shared__ __align__(16) _Float16 Sl[2][64 * SROW];  // 10.25 KB

  const int tid = threadIdx.x;
  const int b   = blockIdx.x;   // 0..7  -> linear%8 -> XCD-affine batch
  const int rp  = blockIdx.y;   // 0..63 -> one output row

  // sampling role: 64 pos x 4 channel-octets (4 lanes = 64 B contiguous per pixel)
  const int pos = tid >> 2, cg = tid & 3;
  const int ho  = rp, wo = pos;
  // MFMA role: 4 waves, each 64(o) x 64(p)
  const int lane = tid & 63, wm = tid >> 6;
  const int lq = lane >> 4, lr = lane & 15;

  const f16x8* gin = (const f16x8*)(inh + (size_t)b * HW * Cc);
  const uint4* wg4 = (const uint4*)wgh;
  const int    wbase = lq * 256 + wm * 64 + lr;   // uint4 index within chunk

  int4   mi_c, mi_n = {0,0,0,0};
  float4 mwt_c, mwt_n = {0,0,0,0};
  float  ofy, ofx, msk;
  f16x8  vc[2][4];               // depth-2 corner sets — static indices only
  uint4  awv[4];

  auto load_md_inputs = [&](int tap) {
    ofy = offset[(((size_t)b * 18 + 2 * tap)     * 64 + ho) * 64 + wo];
    ofx = offset[(((size_t)b * 18 + 2 * tap + 1) * 64 + ho) * 64 + wo];
    msk = mask  [(((size_t)b * 9  + tap)         * 64 + ho) * 64 + wo];
  };
  auto build_md = [&](int tap, int4& mio, float4& mwo) {
    int ki = tap / 3, kj = tap % 3;
    float y = ofy + (float)(ho - 1 + ki);
    float x = ofx + (float)(wo - 1 + kj);
    float y0f = floorf(y), x0f = floorf(x);
    float ly = y - y0f, lx = x - x0f;
    float hy = 1.f - ly, hx = 1.f - lx;
    int y0 = (int)y0f, x0 = (int)x0f;
    int y1 = y0 + 1, x1 = x0 + 1;
    bool vy0 = (unsigned)y0 < 64u, vy1 = (unsigned)y1 < 64u;
    bool vx0 = (unsigned)x0 < 64u, vx1 = (unsigned)x1 < 64u;
    int cy0 = min(max(y0, 0), 63), cy1 = min(max(y1, 0), 63);
    int cx0 = min(max(x0, 0), 63), cx1 = min(max(x1, 0), 63);
    mwo.x = (vy0 && vx0) ? hy * hx * msk : 0.f;
    mwo.y = (vy0 && vx1) ? hy * lx * msk : 0.f;
    mwo.z = (vy1 && vx0) ? ly * hx * msk : 0.f;
    mwo.w = (vy1 && vx1) ? ly * lx * msk : 0.f;
    mio = make_int4(cy0 * 64 + cx0, cy0 * 64 + cx1, cy1 * 64 + cx0, cy1 * 64 + cx1);
  };
  auto gather = [&](const int4& m, int cb8, f16x8* dst) {
    int cb = cb8 + cg;
    dst[0] = gin[m.x * 32 + cb];
    dst[1] = gin[m.y * 32 + cb];
    dst[2] = gin[m.z * 32 + cb];
    dst[3] = gin[m.w * 32 + cb];
  };
  auto stage = [&](const f16x8* v, const float4& w, int buf) {
    f16x8 sv = v[0] * sp8((_Float16)w.x) + v[1] * sp8((_Float16)w.y)
             + v[2] * sp8((_Float16)w.z) + v[3] * sp8((_Float16)w.w);
    *(f16x8*)(&Sl[buf][pos * SROW + cg * 8]) = sv;
  };
  auto wload = [&](int c) {
    const uint4* base = wg4 + (size_t)c * 1024 + wbase;
#pragma unroll
    for (int mt = 0; mt < 4; ++mt) awv[mt] = base[mt * 16];
  };

  f32x4 acc[4][4];
#pragma unroll
  for (int mt = 0; mt < 4; ++mt)
#pragma unroll
    for (int nt = 0; nt < 4; ++nt) {
      acc[mt][nt][0] = 0.f; acc[mt][nt][1] = 0.f;
      acc[mt][nt][2] = 0.f; acc[mt][nt][3] = 0.f;
    }

  // ---- prologue: md(tap0), gather chunks 0,1, weights 0, stage chunk 0 ----
  load_md_inputs(0);
  build_md(0, mi_c, mwt_c);
  gather(mi_c, 0, vc[0]);          // chunk 0 -> set 0
  wload(0);
  gather(mi_c, 4, vc[1]);          // chunk 1 -> set 1
  stage(vc[0], mwt_c, 0);          // Sl[0]
  __syncthreads();

  for (int t = 0; t < 9; ++t) {
#pragma unroll
    for (int j = 0; j < 8; ++j) {          // c = t*8 + j ; all j-indices fold
      const int c   = t * 8 + j;
      const int cur = j & 1;               // == c & 1

      // gathers for chunk c+2 -> set cur (freed by stage(c) last iteration)
      if (j < 6) {
        gather(mi_c, ((j + 2) & 7) * 4, vc[cur]);
      } else if (t < 8) {
        if (j == 6) build_md(t + 1, mi_n, mwt_n);   // inputs loaded at j==4
        gather(mi_n, ((j + 2) & 7) * 4, vc[cur]);
      }
      if (j == 4 && t < 8) load_md_inputs(t + 1);   // 2 chunks ahead of build

      // A-fragments for this chunk (loaded last iteration), then prefetch next
      f16x8 afr[4];
#pragma unroll
      for (int mt = 0; mt < 4; ++mt) afr[mt] = __builtin_bit_cast(f16x8, awv[mt]);
      if (j < 7 || t < 8) wload(c + 1);

      const _Float16* SlB = &Sl[cur][lr * SROW + lq * 8];
#pragma unroll
      for (int nt = 0; nt < 4; ++nt) {
        f16x8 bfr = *(const f16x8*)(SlB + nt * 16 * SROW);
#pragma unroll
        for (int mt = 0; mt < 4; ++mt)
          acc[mt][nt] = __builtin_amdgcn_mfma_f32_16x16x32_f16(afr[mt], bfr, acc[mt][nt], 0, 0, 0);
      }

      // stage chunk c+1 (consume set cur^1) into Sl[cur^1]
      if (j < 7) {
        stage(vc[cur ^ 1], mwt_c, cur ^ 1);
      } else if (t < 8) {
        stage(vc[cur ^ 1], mwt_n, cur ^ 1);         // c+1 starts tap t+1
      }
      barrier_no_vm_drain();               // LDS drained; global loads stay in flight
    }
    if (t < 8) { mi_c = mi_n; mwt_c = mwt_n; }      // rotate md registers
  }

  // ---- epilogue: bias + store ----
#pragma unroll
  for (int mt = 0; mt < 4; ++mt) {
#pragma unroll
    for (int reg = 0; reg < 4; ++reg) {
      int o = wm * 64 + mt * 16 + lq * 4 + reg;
      float bv = bias[o];
      float* op = out + ((size_t)(b * 256 + o)) * 4096 + rp * 64 + lr;
#pragma unroll
      for (int nt = 0; nt < 4; ++nt)
        op[nt * 16] = acc[mt][nt][reg] + bv;
    }
  }
}

extern "C" void kernel_launch(void* const* d_in, const int* in_sizes, int n_in,
                              void* d_out, int out_size, void* d_ws, size_t ws_size,
                              hipStream_t stream) {
  const float* inp    = (const float*)d_in[0];
  const float* offset = (const float*)d_in[1];
  const float* mask   = (const float*)d_in[2];
  const float* weight = (const float*)d_in[3];
  const float* bias   = (const float*)d_in[4];
  float* out = (float*)d_out;

  _Float16* inh = (_Float16*)d_ws;                       // 16.78 MB
  _Float16* wgh = inh + (size_t)Bb * HW * Cc;            // +1.18 MB

  hipLaunchKernelGGL(nchw_to_nhwc_f16, dim3(128, Bb), dim3(256), 0, stream, inp, inh);
  hipLaunchKernelGGL(wcvt, dim3(288), dim3(256), 0, stream, weight, wgh);
  // grid: x=b -> linear%8 = batch -> XCD-affine; y = output row; 2 blocks/CU
  hipLaunchKernelGGL(dcn_mfma, dim3(Bb, 64), dim3(256), 0, stream,
                     inh, wgh, offset, mask, bias, out);
}

// Round 10
// 148.983 us; speedup vs baseline: 22.8752x; 1.0301x over previous
//
#include <hip/hip_runtime.h>

typedef _Float16 f16x8 __attribute__((ext_vector_type(8)));
typedef float    f32x4 __attribute__((ext_vector_type(4)));

namespace {
constexpr int Bb = 8, Cc = 256, Oo = 256;
constexpr int HW = 4096;                 // 64x64
constexpr int NCHUNK = 72;               // 2304 / 32
constexpr int SROW = 40;                 // Sl row stride (f16), pad 32->40
constexpr int TBLK = 512;                // transpose blocks (8 b x 64 px-groups)
}

__device__ inline f16x8 sp8(_Float16 x) { f16x8 r = {x,x,x,x,x,x,x,x}; return r; }

// ---------- fused pre-kernel: [0,512) transpose NCHW->NHWC fp16, [512,800) weight cvt ----------
__global__ __launch_bounds__(256)
void prep(const float* __restrict__ in, const float* __restrict__ w,
          _Float16* __restrict__ outh, _Float16* __restrict__ wh) {
  const int bid = blockIdx.x;
  const int t   = threadIdx.x;
  if (bid < TBLK) {
    // ---- tiled transpose: 64 px x 256 ch per block ----
    __shared__ _Float16 Lt[64][264];           // pad 256->264 (16B-aligned rows)
    const int b = bid >> 6, pxg = bid & 63;
    const float* src = in + (size_t)b * Cc * HW + pxg * 64;
    const int chb = t & 15, quad = t >> 4;     // lanes: 16 ch (fast) x 16 px-quads
#pragma unroll
    for (int ci = 0; ci < 16; ++ci) {
      int ch = ci * 16 + chb;
      float4 v = *(const float4*)(src + (size_t)ch * HW + quad * 4);
      Lt[quad * 4 + 0][ch] = (_Float16)v.x;
      Lt[quad * 4 + 1][ch] = (_Float16)v.y;
      Lt[quad * 4 + 2][ch] = (_Float16)v.z;
      Lt[quad * 4 + 3][ch] = (_Float16)v.w;
    }
    __syncthreads();
    _Float16* dst = outh + ((size_t)b * HW + pxg * 64) * Cc;
    const int c8 = t & 31, pxs = t >> 5;       // 32 c8-octets x 8 px-slots
#pragma unroll
    for (int it = 0; it < 8; ++it) {
      int px = it * 8 + pxs;
      f16x8 v = *(const f16x8*)(&Lt[px][c8 * 8]);
      *(f16x8*)(dst + (size_t)px * Cc + c8 * 8) = v;
    }
  } else {
    // ---- weight fp32 [O][C][9] -> fp16 [chunk][kq][o][k8], K = tap*256+c ----
    int tt = (bid - TBLK) * 256 + t;           // 0..73727
    int o  = tt & 255;
    int Kb = (tt >> 8) * 8;
    const float* s = w + (size_t)o * 2304;
    f16x8 v;
#pragma unroll
    for (int k8 = 0; k8 < 8; ++k8) {
      int K = Kb + k8;
      int tap = K >> 8, c = K & 255;
      v[k8] = (_Float16)s[c * 9 + tap];
    }
    *(f16x8*)(wh + (size_t)tt * 8) = v;
  }
}

// ---------- main kernel: exact R8 (best measured) ----------
// 256(o) x 64(p), 256 thr, 2 blocks/CU, XCD-affine, static depth-2 pipe, __syncthreads.
__global__ __launch_bounds__(256, 2)
void dcn_mfma(const _Float16* __restrict__ inh,   // [B][4096][256] fp16 NHWC
              const _Float16* __restrict__ wgh,   // [72][4][256][8] fp16 (A-frag order)
              const float* __restrict__ offset,
              const float* __restrict__ mask,
              const float* __restrict__ bias,
              float* __restrict__ out) {
  __shared__ __align__(16) _Float16 Sl[2][64 * SROW];  // 10.25 KB

  const int tid = threadIdx.x;
  const int b   = blockIdx.x;   // 0..7  -> linear%8 -> XCD-affine batch
  const int rp  = blockIdx.y;   // 0..63 -> one output row

  const int pos = tid >> 2, cg = tid & 3;
  const int ho  = rp, wo = pos;
  const int lane = tid & 63, wm = tid >> 6;
  const int lq = lane >> 4, lr = lane & 15;

  const f16x8* gin = (const f16x8*)(inh + (size_t)b * HW * Cc);
  const uint4* wg4 = (const uint4*)wgh;
  const int    wbase = lq * 256 + wm * 64 + lr;

  int4   mi_c, mi_n = {0,0,0,0};
  float4 mwt_c, mwt_n = {0,0,0,0};
  float  ofy, ofx, msk;
  f16x8  vc[2][4];
  uint4  awv[4];

  auto load_md_inputs = [&](int tap) {
    ofy = offset[(((size_t)b * 18 + 2 * tap)     * 64 + ho) * 64 + wo];
    ofx = offset[(((size_t)b * 18 + 2 * tap + 1) * 64 + ho) * 64 + wo];
    msk = mask  [(((size_t)b * 9  + tap)         * 64 + ho) * 64 + wo];
  };
  auto build_md = [&](int tap, int4& mio, float4& mwo) {
    int ki = tap / 3, kj = tap % 3;
    float y = ofy + (float)(ho - 1 + ki);
    float x = ofx + (float)(wo - 1 + kj);
    float y0f = floorf(y), x0f = floorf(x);
    float ly = y - y0f, lx = x - x0f;
    float hy = 1.f - ly, hx = 1.f - lx;
    int y0 = (int)y0f, x0 = (int)x0f;
    int y1 = y0 + 1, x1 = x0 + 1;
    bool vy0 = (unsigned)y0 < 64u, vy1 = (unsigned)y1 < 64u;
    bool vx0 = (unsigned)x0 < 64u, vx1 = (unsigned)x1 < 64u;
    int cy0 = min(max(y0, 0), 63), cy1 = min(max(y1, 0), 63);
    int cx0 = min(max(x0, 0), 63), cx1 = min(max(x1, 0), 63);
    mwo.x = (vy0 && vx0) ? hy * hx * msk : 0.f;
    mwo.y = (vy0 && vx1) ? hy * lx * msk : 0.f;
    mwo.z = (vy1 && vx0) ? ly * hx * msk : 0.f;
    mwo.w = (vy1 && vx1) ? ly * lx * msk : 0.f;
    mio = make_int4(cy0 * 64 + cx0, cy0 * 64 + cx1, cy1 * 64 + cx0, cy1 * 64 + cx1);
  };
  auto gather = [&](const int4& m, int cb8, f16x8* dst) {
    int cb = cb8 + cg;
    dst[0] = gin[m.x * 32 + cb];
    dst[1] = gin[m.y * 32 + cb];
    dst[2] = gin[m.z * 32 + cb];
    dst[3] = gin[m.w * 32 + cb];
  };
  auto stage = [&](const f16x8* v, const float4& w, int buf) {
    f16x8 sv = v[0] * sp8((_Float16)w.x) + v[1] * sp8((_Float16)w.y)
             + v[2] * sp8((_Float16)w.z) + v[3] * sp8((_Float16)w.w);
    *(f16x8*)(&Sl[buf][pos * SROW + cg * 8]) = sv;
  };
  auto wload = [&](int c) {
    const uint4* base = wg4 + (size_t)c * 1024 + wbase;
#pragma unroll
    for (int mt = 0; mt < 4; ++mt) awv[mt] = base[mt * 16];
  };

  f32x4 acc[4][4];
#pragma unroll
  for (int mt = 0; mt < 4; ++mt)
#pragma unroll
    for (int nt = 0; nt < 4; ++nt) {
      acc[mt][nt][0] = 0.f; acc[mt][nt][1] = 0.f;
      acc[mt][nt][2] = 0.f; acc[mt][nt][3] = 0.f;
    }

  load_md_inputs(0);
  build_md(0, mi_c, mwt_c);
  gather(mi_c, 0, vc[0]);
  wload(0);
  gather(mi_c, 4, vc[1]);
  stage(vc[0], mwt_c, 0);
  __syncthreads();

  for (int t = 0; t < 9; ++t) {
#pragma unroll
    for (int j = 0; j < 8; ++j) {
      const int c   = t * 8 + j;
      const int cur = j & 1;

      if (j < 6) {
        gather(mi_c, ((j + 2) & 7) * 4, vc[cur]);
      } else if (t < 8) {
        if (j == 6) build_md(t + 1, mi_n, mwt_n);
        gather(mi_n, ((j + 2) & 7) * 4, vc[cur]);
      }
      if (j == 4 && t < 8) load_md_inputs(t + 1);

      f16x8 afr[4];
#pragma unroll
      for (int mt = 0; mt < 4; ++mt) afr[mt] = __builtin_bit_cast(f16x8, awv[mt]);
      if (j < 7 || t < 8) wload(c + 1);

      const _Float16* SlB = &Sl[cur][lr * SROW + lq * 8];
#pragma unroll
      for (int nt = 0; nt < 4; ++nt) {
        f16x8 bfr = *(const f16x8*)(SlB + nt * 16 * SROW);
#pragma unroll
        for (int mt = 0; mt < 4; ++mt)
          acc[mt][nt] = __builtin_amdgcn_mfma_f32_16x16x32_f16(afr[mt], bfr, acc[mt][nt], 0, 0, 0);
      }

      if (j < 7) {
        stage(vc[cur ^ 1], mwt_c, cur ^ 1);
      } else if (t < 8) {
        stage(vc[cur ^ 1], mwt_n, cur ^ 1);
      }
      __syncthreads();
    }
    if (t < 8) { mi_c = mi_n; mwt_c = mwt_n; }
  }

#pragma unroll
  for (int mt = 0; mt < 4; ++mt) {
#pragma unroll
    for (int reg = 0; reg < 4; ++reg) {
      int o = wm * 64 + mt * 16 + lq * 4 + reg;
      float bv = bias[o];
      float* op = out + ((size_t)(b * 256 + o)) * 4096 + rp * 64 + lr;
#pragma unroll
      for (int nt = 0; nt < 4; ++nt)
        op[nt * 16] = acc[mt][nt][reg] + bv;
    }
  }
}

extern "C" void kernel_launch(void* const* d_in, const int* in_sizes, int n_in,
                              void* d_out, int out_size, void* d_ws, size_t ws_size,
                              hipStream_t stream) {
  const float* inp    = (const float*)d_in[0];
  const float* offset = (const float*)d_in[1];
  const float* mask   = (const float*)d_in[2];
  const float* weight = (const float*)d_in[3];
  const float* bias   = (const float*)d_in[4];
  float* out = (float*)d_out;

  _Float16* inh = (_Float16*)d_ws;                       // 16.78 MB
  _Float16* wgh = inh + (size_t)Bb * HW * Cc;            // +1.18 MB

  hipLaunchKernelGGL(prep, dim3(TBLK + 288), dim3(256), 0, stream,
                     inp, weight, inh, wgh);
  // grid: x=b -> linear%8 = batch -> XCD-affine; y = output row; 2 blocks/CU
  hipLaunchKernelGGL(dcn_mfma, dim3(Bb, 64), dim3(256), 0, stream,
                     inh, wgh, offset, mask, bias, out);
}

// Round 11
// 142.941 us; speedup vs baseline: 23.8420x; 1.0423x over previous
//
#include <hip/hip_runtime.h>

typedef _Float16 f16x8 __attribute__((ext_vector_type(8)));
typedef float    f32x4 __attribute__((ext_vector_type(4)));

namespace {
constexpr int Bb = 8, Cc = 256, Oo = 256;
constexpr int HW = 4096;                 // 64x64
constexpr int NCH2 = 36;                 // double-chunks of 64 K (4 per tap)
constexpr int SROW2 = 72;                // Sl row stride (f16): 64 + 8 pad
constexpr int TBLK = 512;                // transpose blocks (8 b x 64 px-groups)
}

__device__ inline f16x8 sp8(_Float16 x) { f16x8 r = {x,x,x,x,x,x,x,x}; return r; }

// ---------- fused pre-kernel (R10 verbatim) ----------
__global__ __launch_bounds__(256)
void prep(const float* __restrict__ in, const float* __restrict__ w,
          _Float16* __restrict__ outh, _Float16* __restrict__ wh) {
  const int bid = blockIdx.x;
  const int t   = threadIdx.x;
  if (bid < TBLK) {
    __shared__ _Float16 Lt[64][264];
    const int b = bid >> 6, pxg = bid & 63;
    const float* src = in + (size_t)b * Cc * HW + pxg * 64;
    const int chb = t & 15, quad = t >> 4;
#pragma unroll
    for (int ci = 0; ci < 16; ++ci) {
      int ch = ci * 16 + chb;
      float4 v = *(const float4*)(src + (size_t)ch * HW + quad * 4);
      Lt[quad * 4 + 0][ch] = (_Float16)v.x;
      Lt[quad * 4 + 1][ch] = (_Float16)v.y;
      Lt[quad * 4 + 2][ch] = (_Float16)v.z;
      Lt[quad * 4 + 3][ch] = (_Float16)v.w;
    }
    __syncthreads();
    _Float16* dst = outh + ((size_t)b * HW + pxg * 64) * Cc;
    const int c8 = t & 31, pxs = t >> 5;
#pragma unroll
    for (int it = 0; it < 8; ++it) {
      int px = it * 8 + pxs;
      f16x8 v = *(const f16x8*)(&Lt[px][c8 * 8]);
      *(f16x8*)(dst + (size_t)px * Cc + c8 * 8) = v;
    }
  } else {
    int tt = (bid - TBLK) * 256 + t;
    int o  = tt & 255;
    int Kb = (tt >> 8) * 8;
    const float* s = w + (size_t)o * 2304;
    f16x8 v;
#pragma unroll
    for (int k8 = 0; k8 < 8; ++k8) {
      int K = Kb + k8;
      int tap = K >> 8, c = K & 255;
      v[k8] = (_Float16)s[c * 9 + tap];
    }
    *(f16x8*)(wh + (size_t)tt * 8) = v;
  }
}

// ---------- main kernel: 256(o) x 64(p), chunk = 64 K, 36 barriers ----------
__global__ __launch_bounds__(256, 2)
void dcn_mfma(const _Float16* __restrict__ inh,   // [B][4096][256] fp16 NHWC
              const _Float16* __restrict__ wgh,   // [72][4][256][8] fp16 (A-frag order)
              const float* __restrict__ offset,
              const float* __restrict__ mask,
              const float* __restrict__ bias,
              float* __restrict__ out) {
  __shared__ __align__(16) _Float16 Sl[2][64 * SROW2];  // 18.4 KB

  const int tid = threadIdx.x;
  const int b   = blockIdx.x;   // 0..7  -> linear%8 -> XCD-affine batch
  const int rp  = blockIdx.y;   // 0..63 -> one output row

  const int pos = tid >> 2, cg = tid & 3;
  const int ho  = rp, wo = pos;
  const int lane = tid & 63, wm = tid >> 6;
  const int lq = lane >> 4, lr = lane & 15;

  const f16x8* gin = (const f16x8*)(inh + (size_t)b * HW * Cc);
  const uint4* wg4 = (const uint4*)wgh;
  const int    wbase = lq * 256 + wm * 64 + lr;

  int4   mi_c, mi_n = {0,0,0,0};
  float4 mwt_c, mwt_n = {0,0,0,0};
  float  ofy, ofx, msk;
  f16x8  vc[2][8];               // depth-2 corner sets, 8 octets (2 per corner)
  uint4  awv[8];                 // A-fragments in flight (both K-halves)

  auto load_md_inputs = [&](int tap) {
    ofy = offset[(((size_t)b * 18 + 2 * tap)     * 64 + ho) * 64 + wo];
    ofx = offset[(((size_t)b * 18 + 2 * tap + 1) * 64 + ho) * 64 + wo];
    msk = mask  [(((size_t)b * 9  + tap)         * 64 + ho) * 64 + wo];
  };
  auto build_md = [&](int tap, int4& mio, float4& mwo) {
    int ki = tap / 3, kj = tap % 3;
    float y = ofy + (float)(ho - 1 + ki);
    float x = ofx + (float)(wo - 1 + kj);
    float y0f = floorf(y), x0f = floorf(x);
    float ly = y - y0f, lx = x - x0f;
    float hy = 1.f - ly, hx = 1.f - lx;
    int y0 = (int)y0f, x0 = (int)x0f;
    int y1 = y0 + 1, x1 = x0 + 1;
    bool vy0 = (unsigned)y0 < 64u, vy1 = (unsigned)y1 < 64u;
    bool vx0 = (unsigned)x0 < 64u, vx1 = (unsigned)x1 < 64u;
    int cy0 = min(max(y0, 0), 63), cy1 = min(max(y1, 0), 63);
    int cx0 = min(max(x0, 0), 63), cx1 = min(max(x1, 0), 63);
    mwo.x = (vy0 && vx0) ? hy * hx * msk : 0.f;
    mwo.y = (vy0 && vx1) ? hy * lx * msk : 0.f;
    mwo.z = (vy1 && vx0) ? ly * hx * msk : 0.f;
    mwo.w = (vy1 && vx1) ? ly * lx * msk : 0.f;
    mio = make_int4(cy0 * 64 + cx0, cy0 * 64 + cx1, cy1 * 64 + cx0, cy1 * 64 + cx1);
  };
  // gather 64 channels (2 octets per corner) for double-chunk cc
  auto gather = [&](const int4& m, int cc, f16x8* dst) {
    int cb = (cc & 3) * 8 + cg;
    dst[0] = gin[m.x * 32 + cb];     dst[1] = gin[m.y * 32 + cb];
    dst[2] = gin[m.z * 32 + cb];     dst[3] = gin[m.w * 32 + cb];
    dst[4] = gin[m.x * 32 + cb + 4]; dst[5] = gin[m.y * 32 + cb + 4];
    dst[6] = gin[m.z * 32 + cb + 4]; dst[7] = gin[m.w * 32 + cb + 4];
  };
  auto stage = [&](const f16x8* v, const float4& w, int buf) {
    f16x8 s0 = v[0] * sp8((_Float16)w.x) + v[1] * sp8((_Float16)w.y)
             + v[2] * sp8((_Float16)w.z) + v[3] * sp8((_Float16)w.w);
    f16x8 s1 = v[4] * sp8((_Float16)w.x) + v[5] * sp8((_Float16)w.y)
             + v[6] * sp8((_Float16)w.z) + v[7] * sp8((_Float16)w.w);
    *(f16x8*)(&Sl[buf][pos * SROW2 + cg * 8])      = s0;
    *(f16x8*)(&Sl[buf][pos * SROW2 + 32 + cg * 8]) = s1;
  };
  auto wload_half = [&](int cc, int h) {     // old-chunk 2cc+h -> awv[4h..4h+3]
    const uint4* base = wg4 + (size_t)(2 * cc + h) * 1024 + wbase;
#pragma unroll
    for (int mt = 0; mt < 4; ++mt) awv[h * 4 + mt] = base[mt * 16];
  };

  f32x4 acc[4][4];
#pragma unroll
  for (int mt = 0; mt < 4; ++mt)
#pragma unroll
    for (int nt = 0; nt < 4; ++nt) {
      acc[mt][nt][0] = 0.f; acc[mt][nt][1] = 0.f;
      acc[mt][nt][2] = 0.f; acc[mt][nt][3] = 0.f;
    }

  // ---- prologue: md(tap0), gather chunks 0,1, weights chunk 0, stage 0 ----
  load_md_inputs(0);
  build_md(0, mi_c, mwt_c);
  gather(mi_c, 0, vc[0]);
  wload_half(0, 0); wload_half(0, 1);
  gather(mi_c, 1, vc[1]);
  stage(vc[0], mwt_c, 0);
  __syncthreads();

  for (int t = 0; t < 9; ++t) {
#pragma unroll
    for (int j = 0; j < 4; ++j) {          // cc = t*4 + j ; all j-indices fold
      const int cc  = t * 4 + j;
      const int cur = j & 1;

      // gathers for chunk cc+2 -> set cur (freed by stage(cc) last iteration)
      if (j < 2) {
        gather(mi_c, cc + 2, vc[cur]);
      } else if (t < 8) {
        if (j == 2) build_md(t + 1, mi_n, mwt_n);   // inputs loaded at j==0
        gather(mi_n, cc + 2, vc[cur]);
      }
      if (j == 0 && t < 8) load_md_inputs(t + 1);

      // K-half 0: copy A-frags, prefetch next chunk's half 0, MFMA
      {
        f16x8 afr[4];
#pragma unroll
        for (int mt = 0; mt < 4; ++mt) afr[mt] = __builtin_bit_cast(f16x8, awv[mt]);
        if (cc + 1 < NCH2) wload_half(cc + 1, 0);
#pragma unroll
        for (int nt = 0; nt < 4; ++nt) {
          f16x8 bfr = *(const f16x8*)(&Sl[cur][(nt * 16 + lr) * SROW2 + lq * 8]);
#pragma unroll
          for (int mt = 0; mt < 4; ++mt)
            acc[mt][nt] = __builtin_amdgcn_mfma_f32_16x16x32_f16(afr[mt], bfr, acc[mt][nt], 0, 0, 0);
        }
      }
      // K-half 1
      {
        f16x8 afr[4];
#pragma unroll
        for (int mt = 0; mt < 4; ++mt) afr[mt] = __builtin_bit_cast(f16x8, awv[4 + mt]);
        if (cc + 1 < NCH2) wload_half(cc + 1, 1);
#pragma unroll
        for (int nt = 0; nt < 4; ++nt) {
          f16x8 bfr = *(const f16x8*)(&Sl[cur][(nt * 16 + lr) * SROW2 + 32 + lq * 8]);
#pragma unroll
          for (int mt = 0; mt < 4; ++mt)
            acc[mt][nt] = __builtin_amdgcn_mfma_f32_16x16x32_f16(afr[mt], bfr, acc[mt][nt], 0, 0, 0);
        }
      }

      // stage chunk cc+1 (consume set cur^1) into Sl[cur^1]
      if (j < 3) {
        stage(vc[cur ^ 1], mwt_c, cur ^ 1);
      } else if (t < 8) {
        stage(vc[cur ^ 1], mwt_n, cur ^ 1);         // cc+1 starts tap t+1
      }
      __syncthreads();
    }
    if (t < 8) { mi_c = mi_n; mwt_c = mwt_n; }
  }

  // ---- epilogue: bias + store ----
#pragma unroll
  for (int mt = 0; mt < 4; ++mt) {
#pragma unroll
    for (int reg = 0; reg < 4; ++reg) {
      int o = wm * 64 + mt * 16 + lq * 4 + reg;
      float bv = bias[o];
      float* op = out + ((size_t)(b * 256 + o)) * 4096 + rp * 64 + lr;
#pragma unroll
      for (int nt = 0; nt < 4; ++nt)
        op[nt * 16] = acc[mt][nt][reg] + bv;
    }
  }
}

extern "C" void kernel_launch(void* const* d_in, const int* in_sizes, int n_in,
                              void* d_out, int out_size, void* d_ws, size_t ws_size,
                              hipStream_t stream) {
  const float* inp    = (const float*)d_in[0];
  const float* offset = (const float*)d_in[1];
  const float* mask   = (const float*)d_in[2];
  const float* weight = (const float*)d_in[3];
  const float* bias   = (const float*)d_in[4];
  float* out = (float*)d_out;

  _Float16* inh = (_Float16*)d_ws;                       // 16.78 MB
  _Float16* wgh = inh + (size_t)Bb * HW * Cc;            // +1.18 MB

  hipLaunchKernelGGL(prep, dim3(TBLK + 288), dim3(256), 0, stream,
                     inp, weight, inh, wgh);
  hipLaunchKernelGGL(dcn_mfma, dim3(Bb, 64), dim3(256), 0, stream,
                     inh, wgh, offset, mask, bias, out);
}